// Round 4
// baseline (17055.910 us; speedup 1.0000x reference)
//
#include <hip/hip_runtime.h>

typedef unsigned short u16;
typedef unsigned int   u32;
typedef short short8 __attribute__((ext_vector_type(8)));
typedef float f32x4  __attribute__((ext_vector_type(4)));

#define AGENT __HIP_MEMORY_SCOPE_AGENT

// ---------- bf16 helpers (raw-bit, RNE) ----------
__device__ __forceinline__ float bf2f(u16 u) {
    u32 x = ((u32)u) << 16;
    return __builtin_bit_cast(float, x);
}
__device__ __forceinline__ u16 f2bf(float f) {
    u32 x = __builtin_bit_cast(u32, f);
    u32 r = (x + 0x7FFFu + ((x >> 16) & 1u)) >> 16;
    return (u16)r;
}
__device__ __forceinline__ float sigmoidf_(float x) { return 1.0f / (1.0f + __expf(-x)); }
// tanh via 2*sigmoid(2x)-1: saturates cleanly at +-1 for any finite input
__device__ __forceinline__ float tanhf_(float x) { return 2.0f / (1.0f + __expf(-2.0f * x)) - 1.0f; }

// =====================================================================
// init: reset all h-exchange tags to 0xFFFF (never matches step tags
// 0..2047, nor 0xAA poison); detect input dtype from x's raw bits.
// fp32 data read as u16 pairs: low halves are random mantissa bits ->
// ~45% have bf16-exponent >= 140 (|v| >= 2^13). Real bf16 N(0,1): 0%.
// grid 32 x 256. ws: hbufT 128KB (2 par x 256 hc x 64 b dwords) | flag.
// =====================================================================
__global__ __launch_bounds__(256) void lstm_init(const u16* __restrict__ xbits,
                                                 u32* __restrict__ hbufT,
                                                 int* __restrict__ flag) {
    int i = blockIdx.x * 256 + threadIdx.x;  // 0..8191
#pragma unroll
    for (int j = 0; j < 4; j++)
        __hip_atomic_store(hbufT + (size_t)i * 4 + j, 0xFFFFu, __ATOMIC_RELAXED, AGENT);
    if (i == 0) {
        int cnt = 0;
        const uint4* p = (const uint4*)xbits;
        for (int j = 0; j < 64; j++) {  // first 1024 u16 of x
            uint4 v = p[j];
            u32 wv[4] = {v.x, v.y, v.z, v.w};
#pragma unroll
            for (int k2 = 0; k2 < 4; k2++) {
                u32 lo = wv[k2] & 0xFFFFu, hi = wv[k2] >> 16;
                cnt += ((lo & 0x7F80u) >= 0x4600u) ? 1 : 0;
                cnt += ((hi & 0x7F80u) >= 0x4600u) ? 1 : 0;
            }
        }
        *flag = cnt;  // fp32 -> ~230, bf16 -> 0
    }
}

// =====================================================================
// Fused persistent LSTM: grid 16 = 4 batch-groups (jB) x 4 hcol-groups (jH),
// 256 threads (4 waves). WG owns batch [16jB,16jB+16) x hcols [64jH,64jH+64).
// Wh AND Wx slices in VGPRs/AGPRs (128+128 regs).
// Sync: tagged-data protocol. hbufT[par][hc][b] dwords = (h_bf16<<16)|step.
// Producers publish with relaxed agent stores (no fence/RMW); consumers
// poll the data words until tag==t-1 (sync and data share one L3 RTT).
// Parity-2 is race-free: observing ALL of a WG's step-t tags implies that
// WG completed all its step-(t-1) poll loads (barrier+data ordering), so
// no reader of the about-to-be-overwritten parity slot is outstanding.
// =====================================================================
__global__ __launch_bounds__(256, 1) void lstm_fused(const void* __restrict__ x,
                                                     const void* __restrict__ Wx,
                                                     const void* __restrict__ Wh,
                                                     const void* __restrict__ bias,
                                                     const void* __restrict__ c0,
                                                     const void* __restrict__ h0,
                                                     u32* __restrict__ hbufT,
                                                     void* __restrict__ out,
                                                     const int* __restrict__ flag) {
    __shared__ __align__(16) u16 hs[2][16 * 264];  // parity-buffered h stage; [m][k+pad]

    const int tid = threadIdx.x;
    const int lane = tid & 63, w = tid >> 6;
    const int q = lane >> 4, n16 = lane & 15;
    const int jB = blockIdx.x & 3, jH = blockIdx.x >> 2;
    const int b0 = jB * 16;
    const int hc = jH * 64 + w * 16 + n16;  // this lane's h column
    const int bq = b0 + q * 4;              // first of 4 batch rows for this lane

    const int isf32 = (*flag > 64);         // wave-uniform runtime dtype switch

    u16* hsc = &hs[0][0];                   // scratch region for weight transpose

    // ---- preload Wh and Wx B-fragments into registers via LDS piece transpose ----
    short8 Bh[4][8];  // [gate][k-step]
    short8 Bx[4][8];

#define PRELOAD_W(Wsrc, Bf)                                                    \
    _Pragma("unroll")                                                          \
    for (int p = 0; p < 16; p++) {                                             \
        const int g = p >> 2, sub = p & 3;                                     \
        const int colg = g * 256 + jH * 64 + sub * 16;                         \
        u16 tmp[16];                                                           \
        if (isf32) {                                                           \
            const float* s = (const float*)(Wsrc) + (size_t)tid * 1024 + colg; \
            _Pragma("unroll")                                                  \
            for (int c = 0; c < 16; c++) tmp[c] = f2bf(s[c]);                  \
        } else {                                                               \
            const u16* s = (const u16*)(Wsrc) + (size_t)tid * 1024 + colg;     \
            *(uint4*)&tmp[0] = *(const uint4*)s;                               \
            *(uint4*)&tmp[8] = *(const uint4*)(s + 8);                         \
        }                                                                      \
        __syncthreads(); /* previous piece fully read */                       \
        _Pragma("unroll")                                                      \
        for (int c = 0; c < 16; c++) hsc[c * 264 + tid] = tmp[c];              \
        __syncthreads();                                                       \
        if (sub == w) {                                                        \
            _Pragma("unroll")                                                  \
            for (int ks = 0; ks < 8; ks++)                                     \
                (Bf)[g][ks] = *(const short8*)&hsc[n16 * 264 + ks * 32 + q * 8];\
        }                                                                      \
    }

    PRELOAD_W(Wh, Bh)
    PRELOAD_W(Wx, Bx)
    __syncthreads();

// x A-fragment loader for timestep t (batch row b0+n16): dtype-adaptive
#define LOADX(t, dst)                                                              \
    if (isf32) {                                                                   \
        const float* xb = (const float*)x + ((size_t)(b0 + n16) * 2048 + (t)) * 256 + q * 8; \
        _Pragma("unroll")                                                          \
        for (int ks = 0; ks < 8; ks++) {                                           \
            u16 tmp[8];                                                            \
            _Pragma("unroll")                                                      \
            for (int j = 0; j < 8; j++) tmp[j] = f2bf(xb[ks * 32 + j]);            \
            (dst)[ks] = *(const short8*)tmp;                                       \
        }                                                                          \
    } else {                                                                       \
        const u16* xb = (const u16*)x + ((size_t)(b0 + n16) * 2048 + (t)) * 256 + q * 8; \
        _Pragma("unroll")                                                          \
        for (int ks = 0; ks < 8; ks++) (dst)[ks] = *(const short8*)(xb + ks * 32); \
    }

    // ---- per-lane constants / state (dtype-adaptive reads) ----
    float bv[4];
#pragma unroll
    for (int g = 0; g < 4; g++)
        bv[g] = isf32 ? ((const float*)bias)[g * 256 + hc]
                      : bf2f(((const u16*)bias)[g * 256 + hc]);

    float creg[4];
#pragma unroll
    for (int r = 0; r < 4; r++)
        creg[r] = isf32 ? ((const float*)c0)[(size_t)(bq + r) * 256 + hc]
                        : bf2f(((const u16*)c0)[(size_t)(bq + r) * 256 + hc]);

    // ---- stage h_{-1} = h0 straight from global into hs[0]: [m][k=tid] ----
#pragma unroll
    for (int m = 0; m < 16; m++) {
        u16 v = isf32 ? f2bf(((const float*)h0)[(size_t)(b0 + m) * 256 + tid])
                      : ((const u16*)h0)[(size_t)(b0 + m) * 256 + tid];
        hs[0][m * 264 + tid] = v;
    }

    // ---- zx for t=0: x[t=0] @ Wx + b ----
    f32x4 zx[4];
    {
        short8 xf[8];
        LOADX(0, xf)
#pragma unroll
        for (int g = 0; g < 4; g++) { f32x4 a = {bv[g], bv[g], bv[g], bv[g]}; zx[g] = a; }
#pragma unroll
        for (int ks = 0; ks < 8; ks++)
#pragma unroll
            for (int g = 0; g < 4; g++)
                zx[g] = __builtin_amdgcn_mfma_f32_16x16x32_bf16(xf[ks], Bx[g][ks], zx[g], 0, 0, 0);
    }

    // ---- sequential scan: 2048 steps ----
    for (int tl = 0; tl < 2048; tl++) {
        const int hsP = tl & 1;
        u16* hsW = &hs[hsP][0];

        // 0. issue x prefetch for t+1 (latency hides under the poll)
        short8 xfn[8];
        if (tl + 1 < 2048) { LOADX(tl + 1, xfn) }

        // 1+2. poll tagged h_{t-1} words (16 in flight) and stage into LDS
        if (tl > 0) {
            const u32 expt = (u32)(tl - 1);
            const int par = (tl - 1) & 1;
            const u32* hp = hbufT + (size_t)par * 16384 + (size_t)tid * 64 + b0;
            u32 hv[16];
            int guard = 0;
            for (;;) {
#pragma unroll
                for (int i = 0; i < 16; i++)
                    hv[i] = __hip_atomic_load(hp + i, __ATOMIC_RELAXED, AGENT);
                u32 ok = 1;
#pragma unroll
                for (int i = 0; i < 16; i++)
                    ok &= (u32)((hv[i] & 0xFFFFu) == expt);
                if (ok) break;
                if (++guard > (1 << 22)) break;  // safety: garbage instead of hang
                __builtin_amdgcn_s_sleep(1);
            }
#pragma unroll
            for (int m = 0; m < 16; m++)
                hsW[m * 264 + tid] = (u16)(hv[m] >> 16);
        }
        __syncthreads();  // hs[hsP] visible to all waves (covers h0 pre-stage at tl=0)

        // 3. z = zx + h @ Wh
        f32x4 acc[4];
#pragma unroll
        for (int g = 0; g < 4; g++) acc[g] = zx[g];
#pragma unroll
        for (int ks = 0; ks < 8; ks++) {
            short8 af = *(const short8*)&hsW[n16 * 264 + ks * 32 + q * 8];
#pragma unroll
            for (int g = 0; g < 4; g++)
                acc[g] = __builtin_amdgcn_mfma_f32_16x16x32_bf16(af, Bh[g][ks], acc[g], 0, 0, 0);
        }

        // 4. gates + state update; publish tagged h immediately (no fence)
        float hf[4];
        u16 hb[4];
#pragma unroll
        for (int r = 0; r < 4; r++) {
            float ig = sigmoidf_(acc[0][r]);
            float fg = sigmoidf_(acc[1][r]);
            float gg = tanhf_(acc[2][r]);
            float og = sigmoidf_(acc[3][r]);
            float cn = fg * creg[r] + ig * gg;
            creg[r] = cn;
            hf[r] = og * tanhf_(cn);
            hb[r] = f2bf(hf[r]);
        }
        {
            u32* hw = hbufT + (size_t)(tl & 1) * 16384 + (size_t)hc * 64 + bq;
#pragma unroll
            for (int r = 0; r < 4; r++)
                __hip_atomic_store(hw + r, ((u32)hb[r] << 16) | (u32)tl,
                                   __ATOMIC_RELAXED, AGENT);
        }

        // 5. off-critical-path: zx for next step, then out stores
        if (tl + 1 < 2048) {
#pragma unroll
            for (int g = 0; g < 4; g++) { f32x4 a = {bv[g], bv[g], bv[g], bv[g]}; zx[g] = a; }
#pragma unroll
            for (int ks = 0; ks < 8; ks++)
#pragma unroll
                for (int g = 0; g < 4; g++)
                    zx[g] = __builtin_amdgcn_mfma_f32_16x16x32_bf16(xfn[ks], Bx[g][ks], zx[g], 0, 0, 0);
        }
#pragma unroll
        for (int r = 0; r < 4; r++) {
            size_t oi = ((size_t)(bq + r) * 2048 + tl) * 256 + hc;
            if (isf32) ((float*)out)[oi] = hf[r];
            else       ((u16*)out)[oi] = hb[r];
        }
    }
}

// =====================================================================
extern "C" void kernel_launch(void* const* d_in, const int* in_sizes, int n_in,
                              void* d_out, int out_size, void* d_ws, size_t ws_size,
                              hipStream_t stream) {
    const void* x    = d_in[0];
    const void* Wx   = d_in[1];
    const void* Wh   = d_in[2];
    const void* bias = d_in[3];
    const void* h0   = d_in[4];
    const void* c0   = d_in[5];

    // ws layout: hbufT (2*16384 u32 = 128KB) | flag (4B)
    u32* hbufT = (u32*)d_ws;
    int* flag = (int*)((char*)d_ws + 131072);

    lstm_init<<<32, 256, 0, stream>>>((const u16*)x, hbufT, flag);
    lstm_fused<<<16, 256, 0, stream>>>(x, Wx, Wh, bias, c0, h0, hbufT, d_out, flag);
}